// Round 1
// baseline (521.704 us; speedup 1.0000x reference)
//
#include <hip/hip_runtime.h>

// Complete K=8-ary tree, DEPTH=5.
// Level starts: L0:0, L1:1, L2:9, L3:73, L4:585, leaves:4681..37448.
constexpr int NUM_NODES = 37449;
constexpr int L5 = 4681;   // leaf start (32768 leaves)
constexpr int L4 = 585;    // 4096 nodes
constexpr int L3 = 73;     // 512 nodes
constexpr int L2 = 9;      // 64 nodes
constexpr int L1 = 1;      // 8 nodes
constexpr int NLEAF = 32768;

__global__ void sigw_kernel(const float* __restrict__ w, float* __restrict__ sigw) {
    int i = blockIdx.x * blockDim.x + threadIdx.x;
    if (i < NUM_NODES) sigw[i] = 1.0f / (1.0f + __expf(-w[i]));
}

__device__ __forceinline__ float clamp01(float x) {
    return fminf(fmaxf(x, 0.0f), 1.0f);
}

// One block per batch row. Leaves streamed coalesced; groups of 8 lanes
// reduce via shfl_xor (wave=64: masks 1,2,4 stay within an 8-lane group).
// Upper levels run out of LDS (stride-1 reads: 2-way bank alias = free).
__global__ __launch_bounds__(256, 8)
void tree_kernel(const float* __restrict__ in, const float* __restrict__ sigw,
                 float* __restrict__ out) {
    __shared__ float l4s[4096];
    __shared__ float l3s[512];
    __shared__ float l2s[64];
    __shared__ float l1s[8];

    const int t = threadIdx.x;
    const size_t base = (size_t)blockIdx.x * NUM_NODES;
    const float* __restrict__ rin = in + base;
    float* __restrict__ rout = out + base;

    // Stage 1: leaves -> level-4; pass-through copy of leaves.
    // Internal-node INPUT values are never read (they are fully overwritten).
    for (int i = t; i < NLEAF; i += 256) {
        const int node = L5 + i;
        float v = rin[node];
        rout[node] = v;
        float s = v * sigw[node];
        s += __shfl_xor(s, 1);
        s += __shfl_xor(s, 2);
        s += __shfl_xor(s, 4);
        if ((t & 7) == 0) l4s[i >> 3] = clamp01(s);
    }
    __syncthreads();

    // Stage 2: level-4 -> level-3; write level-4 out (coalesced from LDS).
    for (int i = t; i < 4096; i += 256) {
        float v = l4s[i];
        rout[L4 + i] = v;
        float s = v * sigw[L4 + i];
        s += __shfl_xor(s, 1);
        s += __shfl_xor(s, 2);
        s += __shfl_xor(s, 4);
        if ((t & 7) == 0) l3s[i >> 3] = clamp01(s);
    }
    __syncthreads();

    // Stage 3: level-3 -> level-2; write level-3 out.
    for (int i = t; i < 512; i += 256) {
        float v = l3s[i];
        rout[L3 + i] = v;
        float s = v * sigw[L3 + i];
        s += __shfl_xor(s, 1);
        s += __shfl_xor(s, 2);
        s += __shfl_xor(s, 4);
        if ((t & 7) == 0) l2s[i >> 3] = clamp01(s);
    }
    __syncthreads();

    // Stage 4: level-2 -> level-1; write level-2 out.
    if (t < 64) {
        float v = l2s[t];
        rout[L2 + t] = v;
        float s = v * sigw[L2 + t];
        s += __shfl_xor(s, 1);
        s += __shfl_xor(s, 2);
        s += __shfl_xor(s, 4);
        if ((t & 7) == 0) l1s[t >> 3] = clamp01(s);
    }
    __syncthreads();

    // Stage 5: level-1 -> root; write level-1 out.
    if (t < 8) {
        float v = l1s[t];
        rout[L1 + t] = v;
        float s = v * sigw[L1 + t];
        s += __shfl_xor(s, 1);
        s += __shfl_xor(s, 2);
        s += __shfl_xor(s, 4);
        if (t == 0) rout[0] = clamp01(s);
    }
}

extern "C" void kernel_launch(void* const* d_in, const int* in_sizes, int n_in,
                              void* d_out, int out_size, void* d_ws, size_t ws_size,
                              hipStream_t stream) {
    const float* probs = (const float*)d_in[0];   // [batch, NUM_NODES] fp32
    const float* w     = (const float*)d_in[1];   // [NUM_NODES] fp32
    float* out  = (float*)d_out;
    float* sigw = (float*)d_ws;                   // 37449*4 B = 150 KB scratch

    const int batch = in_sizes[0] / NUM_NODES;    // 2048

    hipLaunchKernelGGL(sigw_kernel, dim3((NUM_NODES + 255) / 256), dim3(256), 0,
                       stream, w, sigw);
    hipLaunchKernelGGL(tree_kernel, dim3(batch), dim3(256), 0, stream,
                       probs, sigw, out);
}